// Round 9
// baseline (32.715 us; speedup 1.0000x reference)
//
#include <hip/hip_runtime.h>

#define HDIM 1024
#define GS 8
#define NBR 4.0f
#define HIST_APB 4096       // agents per histogram block (16 per thread)
#define NSP 32              // spread rows for partial accumulation

// ---------------------------------------------------------------------------
// Mask/cell computation — MUST be bit-identical between k_hist and k_reduce.
// ---------------------------------------------------------------------------
__device__ __forceinline__ int agent_cell(float px, float py, float p0x, float p0y,
                                          int i, int idx, bool* m)
{
    float dx = px - p0x, dy = py - p0y;
    *m = (fmaxf(fabsf(dx), fabsf(dy)) <= NBR) && (i != idx);
    float vx = fminf(fmaxf((dx / NBR + 1.0f) * 0.5f * (float)GS, 0.0f), (float)(GS - 1));
    float vy = fminf(fmaxf((dy / NBR + 1.0f) * 0.5f * (float)GS, 0.0f), (float)(GS - 1));
    return (int)vy * GS + (int)vx;   // truncation == floor (>=0)
}

// ---------------------------------------------------------------------------
// Kernel 1: per-block histogram to a private slot; also zeroes partials.
// No cross-block communication (the last-arrival publish from R8 was racy
// because a poisoned counter makes the "last" arrival fire early).
// ---------------------------------------------------------------------------
__launch_bounds__(256)
__global__ void k_hist(const float2* __restrict__ pos, const int* __restrict__ idxp,
                       int n, int* __restrict__ hist_g, float* __restrict__ partials)
{
    __shared__ int hist[64];
    int tid = threadIdx.x;
    if (tid < 64) hist[tid] = 0;
    __syncthreads();

    int idx = idxp[0];
    float2 p0 = pos[idx];

    int a0 = blockIdx.x * HIST_APB + tid * 16;
    if (a0 + 16 <= n) {
        const float4* pp = (const float4*)pos;
#pragma unroll
        for (int k = 0; k < 8; ++k) {
            float4 q = pp[(a0 >> 1) + k];
            bool m0, m1;
            int c0 = agent_cell(q.x, q.y, p0.x, p0.y, a0 + 2 * k,     idx, &m0);
            int c1 = agent_cell(q.z, q.w, p0.x, p0.y, a0 + 2 * k + 1, idx, &m1);
            if (m0) atomicAdd(&hist[c0], 1);
            if (m1) atomicAdd(&hist[c1], 1);
        }
    } else {
        for (int k = 0; k < 16; ++k) {
            int i = a0 + k;
            if (i < n) {
                float2 p = pos[i];
                bool m;
                int c = agent_cell(p.x, p.y, p0.x, p0.y, i, idx, &m);
                if (m) atomicAdd(&hist[c], 1);
            }
        }
    }
    __syncthreads();
    if (tid < 64) hist_g[blockIdx.x * 64 + tid] = hist[tid];

    // zero partial-accumulation rows (grid-stride covers NSP rows)
    for (int r = blockIdx.x; r < NSP; r += gridDim.x)
        ((float4*)(partials + (size_t)r * HDIM))[tid] = make_float4(0.f, 0.f, 0.f, 0.f);
}

// ---------------------------------------------------------------------------
// Kernel 1.5: single tiny block sums the histogram table -> inv_g[65]
// (inv_g[64] = 0 sentinel weight). Kernel boundary gives visibility/order.
// ---------------------------------------------------------------------------
__launch_bounds__(256)
__global__ void k_weights(const int* __restrict__ hist_g, int nbh,
                          float* __restrict__ inv_g)
{
    __shared__ int cnt2[64];
    int tid = threadIdx.x;
    if (tid < 64) cnt2[tid] = 0;
    __syncthreads();

    // thread t sums cell t&63 over row-slice t>>6 (4-way MLP)
    {
        int c = tid & 63, s = 0;
        for (int b = tid >> 6; b < nbh; b += 4)
            s += hist_g[b * 64 + c];
        atomicAdd(&cnt2[c], s);
    }
    __syncthreads();
    if (tid < 64) inv_g[tid] = 1.0f / (float)(cnt2[tid] > 1 ? cnt2[tid] : 1);
    if (tid == 64) inv_g[64] = 0.0f;                     // sentinel weight
}

// ---------------------------------------------------------------------------
// Kernel 2: one 256-agent tile per block. Load the prebuilt inv table (260 B,
// L2-broadcast); recompute mask/cell inline; ballot-compact; pad to multiple
// of 16 with sentinels; branch-free 16-deep gather; spread-atomic accumulate
// into partials[blk % NSP].
// ---------------------------------------------------------------------------
__launch_bounds__(256)
__global__ void k_reduce(const float* __restrict__ h, const float2* __restrict__ pos,
                         const int* __restrict__ idxp, const float* __restrict__ inv_g,
                         int n, float* __restrict__ partials)
{
    __shared__ float inv[65];
    __shared__ int   llist[272];
    __shared__ int   wcnt[4];

    int tid  = threadIdx.x;
    int wave = tid >> 6, lane = tid & 63;

    if (tid < 65) inv[tid] = inv_g[tid];

    // inline mask/cell for this tile
    int idx = idxp[0];
    float2 p0 = pos[idx];
    int i = blockIdx.x * 256 + tid;
    bool m = false;
    int cv = 0;
    if (i < n) {
        float2 p = pos[i];
        cv = agent_cell(p.x, p.y, p0.x, p0.y, i, idx, &m);
    }

    // deterministic ballot compaction
    unsigned long long bal = __ballot(m);
    if (lane == 0) wcnt[wave] = __popcll(bal);
    int ppos = __popcll(bal & ((1ull << lane) - 1ull));
    __syncthreads();

    int off = 0;
    for (int w2 = 0; w2 < wave; ++w2) off += wcnt[w2];
    int lc = wcnt[0] + wcnt[1] + wcnt[2] + wcnt[3];
    int lcp = (lc + 15) & ~15;               // padded length (multiple of 16)
    if (m) llist[off + ppos] = (i << 8) | cv;
    if (tid >= lc && tid < lcp) llist[tid] = 64;   // sentinel: row 0, weight 0
    __syncthreads();

    if (lcp == 0) return;

    // branch-free gather-reduce, 16 rows in flight
    float4 acc = make_float4(0.f, 0.f, 0.f, 0.f);
    for (int g = 0; g < lcp; g += 16) {
        int e[16];
        float4 v[16];
#pragma unroll
        for (int k = 0; k < 16; ++k) e[k] = llist[g + k];
#pragma unroll
        for (int k = 0; k < 16; ++k)
            v[k] = ((const float4*)(h + (size_t)(e[k] >> 8) * HDIM))[tid];
#pragma unroll
        for (int k = 0; k < 16; ++k) {
            float w = inv[e[k] & 255];
            acc.x += w * v[k].x; acc.y += w * v[k].y;
            acc.z += w * v[k].z; acc.w += w * v[k].w;
        }
    }

    float* pr = partials + (size_t)(blockIdx.x & (NSP - 1)) * HDIM + tid * 4;
    atomicAdd(&pr[0], acc.x);
    atomicAdd(&pr[1], acc.y);
    atomicAdd(&pr[2], acc.z);
    atomicAdd(&pr[3], acc.w);
}

// ---------------------------------------------------------------------------
// Kernel 3: combine NSP partial rows in LDS, then out[j] = W[j,:].pooled + b[j]
// (4 rows per block, one row per wave).
// ---------------------------------------------------------------------------
__launch_bounds__(256)
__global__ void k_matvec(const float* __restrict__ W, const float* __restrict__ bvec,
                         const float* __restrict__ partials, float* __restrict__ out)
{
    __shared__ float pooled_s[HDIM];
    int tid  = threadIdx.x;
    int wave = tid >> 6, lane = tid & 63;

    float4 s = make_float4(0.f, 0.f, 0.f, 0.f);
#pragma unroll 8
    for (int r = 0; r < NSP; ++r) {
        float4 v = ((const float4*)(partials + (size_t)r * HDIM))[tid];
        s.x += v.x; s.y += v.y; s.z += v.z; s.w += v.w;
    }
    ((float4*)pooled_s)[tid] = s;
    __syncthreads();

    int j = blockIdx.x * 4 + wave;
    const float4* Wr = (const float4*)(W + (size_t)j * HDIM);
    float d = 0.f;
#pragma unroll
    for (int q = 0; q < 4; ++q) {
        float4 wv = Wr[lane + q * 64];
        float4 pv = ((const float4*)pooled_s)[lane + q * 64];
        d += wv.x * pv.x + wv.y * pv.y + wv.z * pv.z + wv.w * pv.w;
    }

    for (int offr = 32; offr > 0; offr >>= 1)
        d += __shfl_down(d, offr, 64);

    if (lane == 0)
        out[j] = d + bvec[j];
}

extern "C" void kernel_launch(void* const* d_in, const int* in_sizes, int n_in,
                              void* d_out, int out_size, void* d_ws, size_t ws_size,
                              hipStream_t stream) {
    const float*  h    = (const float*)d_in[0];
    const float2* pos  = (const float2*)d_in[1];
    const int*    idxp = (const int*)d_in[2];
    const float*  W    = (const float*)d_in[3];
    const float*  bvec = (const float*)d_in[4];
    float* out = (float*)d_out;

    int n = in_sizes[0] / HDIM;   // number of agents

    int nbh = (n + HIST_APB - 1) / HIST_APB;     // histogram blocks (~25)
    int nbr = (n + 255) / 256;                   // reduce blocks (256-agent tiles)

    char* ws = (char*)d_ws;
    int*   hist_g   = (int*)ws;                                   // nbh*64 ints
    size_t off1 = ((size_t)nbh * 64 * 4 + 255) & ~(size_t)255;
    float* inv_g    = (float*)(ws + off1);                        // 65 floats
    size_t off2 = off1 + 512;
    float* partials = (float*)(ws + off2);                        // NSP*1024 floats

    // all intermediates fully (re)written each call: no memset node needed
    k_hist   <<<nbh, 256, 0, stream>>>(pos, idxp, n, hist_g, partials);
    k_weights<<<1,   256, 0, stream>>>(hist_g, nbh, inv_g);
    k_reduce <<<nbr, 256, 0, stream>>>(h, pos, idxp, inv_g, n, partials);
    k_matvec <<<HDIM / 4, 256, 0, stream>>>(W, bvec, partials, out);
}

// Round 10
// 29.966 us; speedup vs baseline: 1.0917x; 1.0917x over previous
//
#include <hip/hip_runtime.h>

#define HDIM 1024
#define GS 8
#define NBR 4.0f
#define HIST_APB 4096       // agents per histogram block (16 per thread)
#define NSP 16              // spread rows for partial accumulation

// ---------------------------------------------------------------------------
// Mask/cell computation — MUST be bit-identical between k_hist and k_reduce.
// ---------------------------------------------------------------------------
__device__ __forceinline__ int agent_cell(float px, float py, float p0x, float p0y,
                                          int i, int idx, bool* m)
{
    float dx = px - p0x, dy = py - p0y;
    *m = (fmaxf(fabsf(dx), fabsf(dy)) <= NBR) && (i != idx);
    float vx = fminf(fmaxf((dx / NBR + 1.0f) * 0.5f * (float)GS, 0.0f), (float)(GS - 1));
    float vy = fminf(fmaxf((dy / NBR + 1.0f) * 0.5f * (float)GS, 0.0f), (float)(GS - 1));
    return (int)vy * GS + (int)vx;   // truncation == floor (>=0)
}

// ---------------------------------------------------------------------------
// Kernel 1: per-block histogram to a private slot; also zeroes partials.
// ---------------------------------------------------------------------------
__launch_bounds__(256)
__global__ void k_hist(const float2* __restrict__ pos, const int* __restrict__ idxp,
                       int n, int* __restrict__ hist_g, float* __restrict__ partials)
{
    __shared__ int hist[64];
    int tid = threadIdx.x;
    if (tid < 64) hist[tid] = 0;
    __syncthreads();

    int idx = idxp[0];
    float2 p0 = pos[idx];

    int a0 = blockIdx.x * HIST_APB + tid * 16;
    if (a0 + 16 <= n) {
        const float4* pp = (const float4*)pos;
#pragma unroll
        for (int k = 0; k < 8; ++k) {
            float4 q = pp[(a0 >> 1) + k];
            bool m0, m1;
            int c0 = agent_cell(q.x, q.y, p0.x, p0.y, a0 + 2 * k,     idx, &m0);
            int c1 = agent_cell(q.z, q.w, p0.x, p0.y, a0 + 2 * k + 1, idx, &m1);
            if (m0) atomicAdd(&hist[c0], 1);
            if (m1) atomicAdd(&hist[c1], 1);
        }
    } else {
        for (int k = 0; k < 16; ++k) {
            int i = a0 + k;
            if (i < n) {
                float2 p = pos[i];
                bool m;
                int c = agent_cell(p.x, p.y, p0.x, p0.y, i, idx, &m);
                if (m) atomicAdd(&hist[c], 1);
            }
        }
    }
    __syncthreads();
    if (tid < 64) hist_g[blockIdx.x * 64 + tid] = hist[tid];

    // zero partial-accumulation rows (grid-stride covers NSP rows)
    for (int r = blockIdx.x; r < NSP; r += gridDim.x)
        ((float4*)(partials + (size_t)r * HDIM))[tid] = make_float4(0.f, 0.f, 0.f, 0.f);
}

// ---------------------------------------------------------------------------
// Kernel 2: one 256-agent tile per block. Sum the (small) histogram table ->
// inv weights; recompute mask/cell inline from pos; ballot-compact; pad to
// multiple of 8 with sentinels; branch-free 8-deep gather; spread-atomic
// accumulate into partials[blk % NSP].
// ---------------------------------------------------------------------------
__launch_bounds__(256)
__global__ void k_reduce(const float* __restrict__ h, const float2* __restrict__ pos,
                         const int* __restrict__ idxp, const int* __restrict__ hist_g,
                         int nbh, int n, float* __restrict__ partials)
{
    __shared__ int   cnt[64];
    __shared__ float inv[65];
    __shared__ int   llist[264];
    __shared__ int   wcnt[4];

    int tid  = threadIdx.x;
    int wave = tid >> 6, lane = tid & 63;

    if (tid < 64) cnt[tid] = 0;
    __syncthreads();

    // ---- per-cell counts: sum of per-block histograms (nbh ~ 25 rows) ----
    {
        int s = 0;
        for (int b = wave; b < nbh; b += 4)
            s += hist_g[b * 64 + lane];
        atomicAdd(&cnt[lane], s);
    }

    // ---- inline mask/cell for this tile (overlaps with hist loads) ----
    int idx = idxp[0];
    float2 p0 = pos[idx];
    int i = blockIdx.x * 256 + tid;
    bool m = false;
    int cv = 0;
    if (i < n) {
        float2 p = pos[i];
        cv = agent_cell(p.x, p.y, p0.x, p0.y, i, idx, &m);
    }

    __syncthreads();
    if (tid < 64) inv[tid] = 1.0f / (float)(cnt[tid] > 1 ? cnt[tid] : 1);
    if (tid == 64) inv[64] = 0.0f;           // sentinel weight

    // ---- deterministic ballot compaction ----
    unsigned long long bal = __ballot(m);
    if (lane == 0) wcnt[wave] = __popcll(bal);
    int ppos = __popcll(bal & ((1ull << lane) - 1ull));
    __syncthreads();

    int off = 0;
    for (int w2 = 0; w2 < wave; ++w2) off += wcnt[w2];
    int lc = wcnt[0] + wcnt[1] + wcnt[2] + wcnt[3];
    int lcp = (lc + 7) & ~7;                 // padded length
    if (m) llist[off + ppos] = (i << 8) | cv;
    if (tid >= lc && tid < lcp) llist[tid] = 64;   // sentinel: row 0, weight 0
    __syncthreads();

    if (lcp == 0) return;

    // ---- branch-free gather-reduce, 8 rows in flight ----
    float4 acc = make_float4(0.f, 0.f, 0.f, 0.f);
    for (int g = 0; g < lcp; g += 8) {
        int e[8];
        float4 v[8];
#pragma unroll
        for (int k = 0; k < 8; ++k) e[k] = llist[g + k];
#pragma unroll
        for (int k = 0; k < 8; ++k)
            v[k] = ((const float4*)(h + (size_t)(e[k] >> 8) * HDIM))[tid];
#pragma unroll
        for (int k = 0; k < 8; ++k) {
            float w = inv[e[k] & 255];
            acc.x += w * v[k].x; acc.y += w * v[k].y;
            acc.z += w * v[k].z; acc.w += w * v[k].w;
        }
    }

    float* pr = partials + (size_t)(blockIdx.x & (NSP - 1)) * HDIM + tid * 4;
    atomicAdd(&pr[0], acc.x);
    atomicAdd(&pr[1], acc.y);
    atomicAdd(&pr[2], acc.z);
    atomicAdd(&pr[3], acc.w);
}

// ---------------------------------------------------------------------------
// Kernel 3: combine NSP partial rows in LDS, then out[j] = W[j,:].pooled + b[j]
// (4 rows per block, one row per wave).
// ---------------------------------------------------------------------------
__launch_bounds__(256)
__global__ void k_matvec(const float* __restrict__ W, const float* __restrict__ bvec,
                         const float* __restrict__ partials, float* __restrict__ out)
{
    __shared__ float pooled_s[HDIM];
    int tid  = threadIdx.x;
    int wave = tid >> 6, lane = tid & 63;

    float4 s = make_float4(0.f, 0.f, 0.f, 0.f);
#pragma unroll
    for (int r = 0; r < NSP; ++r) {
        float4 v = ((const float4*)(partials + (size_t)r * HDIM))[tid];
        s.x += v.x; s.y += v.y; s.z += v.z; s.w += v.w;
    }
    ((float4*)pooled_s)[tid] = s;
    __syncthreads();

    int j = blockIdx.x * 4 + wave;
    const float4* Wr = (const float4*)(W + (size_t)j * HDIM);
    float d = 0.f;
#pragma unroll
    for (int q = 0; q < 4; ++q) {
        float4 wv = Wr[lane + q * 64];
        float4 pv = ((const float4*)pooled_s)[lane + q * 64];
        d += wv.x * pv.x + wv.y * pv.y + wv.z * pv.z + wv.w * pv.w;
    }

    for (int offr = 32; offr > 0; offr >>= 1)
        d += __shfl_down(d, offr, 64);

    if (lane == 0)
        out[j] = d + bvec[j];
}

extern "C" void kernel_launch(void* const* d_in, const int* in_sizes, int n_in,
                              void* d_out, int out_size, void* d_ws, size_t ws_size,
                              hipStream_t stream) {
    const float*  h    = (const float*)d_in[0];
    const float2* pos  = (const float2*)d_in[1];
    const int*    idxp = (const int*)d_in[2];
    const float*  W    = (const float*)d_in[3];
    const float*  bvec = (const float*)d_in[4];
    float* out = (float*)d_out;

    int n = in_sizes[0] / HDIM;   // number of agents

    int nbh = (n + HIST_APB - 1) / HIST_APB;     // histogram blocks (~25)
    int nbr = (n + 255) / 256;                   // reduce blocks (256-agent tiles)

    char* ws = (char*)d_ws;
    int*   hist_g   = (int*)ws;                                   // nbh*64 ints
    size_t off1 = ((size_t)nbh * 64 * 4 + 255) & ~(size_t)255;
    float* partials = (float*)(ws + off1);                        // NSP*1024 floats

    // all intermediates fully (re)written each call: no memset node needed
    k_hist  <<<nbh, 256, 0, stream>>>(pos, idxp, n, hist_g, partials);
    k_reduce<<<nbr, 256, 0, stream>>>(h, pos, idxp, hist_g, nbh, n, partials);
    k_matvec<<<HDIM / 4, 256, 0, stream>>>(W, bvec, partials, out);
}